// Round 16
// baseline (2632.142 us; speedup 1.0000x reference)
//
#include <hip/hip_runtime.h>

#define TLEN 1024
#define HID  96
#define NTHR 768

typedef float __attribute__((ext_vector_type(2))) f32x2;

__device__ __forceinline__ float sigf(float x) { return 1.0f / (1.0f + __expf(-x)); }
__device__ __forceinline__ float tanh_fast(float x) {
    float e = __expf(2.0f * x);
    return 1.0f - 2.0f / (e + 1.0f);
}

template <int CTRL>
__device__ __forceinline__ float dpp_add(float s) {
    int t = __builtin_amdgcn_update_dpp(0, __float_as_int(s), CTRL, 0xF, 0xF, true);
    return s + __int_as_float(t);
}
#define DPP_XOR1   0xB1   // quad_perm [1,0,3,2]
#define DPP_XOR2   0x4E   // quad_perm [2,3,0,1]
#define DPP_HMIRR  0x141  // row_half_mirror
// full 8-slice sum lands in ALL 8 lanes (R14/R15-verified)
#define RED8(S)  S = dpp_add<DPP_XOR1>(S); S = dpp_add<DPP_XOR2>(S); S = dpp_add<DPP_HMIRR>(S);

// packed 2-wide fp32 FMA; all operands are NATIVE f32x2 register pairs — no
// per-use float4 -> f32x2 repacking (R15's lo2/hi2 cost ~100+ movs/thread/step)
#define PKFMA(ACC, W, H) \
    asm("v_pk_fma_f32 %0, %1, %2, %0" : "+v"(ACC) : "v"(W), "v"(H))

extern "C" __global__ void __launch_bounds__(NTHR)
__attribute__((amdgpu_waves_per_eu(3, 3)))
lstm2_fused(const float* __restrict__ x,
            const float* __restrict__ Wih0, const float* __restrict__ Whh0,
            const float* __restrict__ bih0, const float* __restrict__ bhh0,
            const float* __restrict__ Wih1, const float* __restrict__ Whh1,
            const float* __restrict__ bih1, const float* __restrict__ bhh1,
            const float* __restrict__ Wl,   const float* __restrict__ bl,
            float* __restrict__ out)
{
    __shared__ __attribute__((aligned(16))) float  x_s[TLEN];
    __shared__ __attribute__((aligned(16))) float  out_s[TLEN];
    __shared__ __attribute__((aligned(16))) float  h1b[2 * HID];  // double-buffered
    __shared__ __attribute__((aligned(16))) float  h2b[2 * HID];
    __shared__ __attribute__((aligned(16))) float4 biasb[HID];
    __shared__ __attribute__((aligned(16))) float4 wxb[HID];
    __shared__ __attribute__((aligned(16))) float4 biasd[HID];
    __shared__ __attribute__((aligned(16))) float  wls[HID];
    // gate-o L2 weights as f32x2 planes [k][tid]: 8B/lane stride -> 2 lanes/bank
    // (free, m136); ds_read_b64 natively feeds pk_fma
    __shared__ __attribute__((aligned(16))) f32x2 wlds2[12][NTHR]; // 73,728 B
    // ~88.5 KB -> 1 block/CU, 3 waves/EU (R13-R15-proven no-spill budget)

    const int tid = threadIdx.x;
    const int b   = blockIdx.x;
    const int u   = tid >> 3;
    const int kq  = tid & 7;

    for (int i = tid; i < TLEN; i += NTHR) {
        x_s[i]   = x[b * TLEN + i];
        out_s[i] = 0.0f;
    }

    // ---- Layer-1 weights (regs, native f32x2): gate g row 96g+u, pair-cols 6kq.. ----
    const f32x2* W02 = reinterpret_cast<const f32x2*>(Whh0);  // rows of 48 pairs
    const f32x2* pa;
    pa = W02 + (      u) * 48 + 6 * kq;
    f32x2 a00=pa[0], a01=pa[1], a02=pa[2], a03=pa[3], a04=pa[4], a05=pa[5];
    pa = W02 + ( 96 + u) * 48 + 6 * kq;
    f32x2 a10=pa[0], a11=pa[1], a12=pa[2], a13=pa[3], a14=pa[4], a15=pa[5];
    pa = W02 + (192 + u) * 48 + 6 * kq;
    f32x2 a20=pa[0], a21=pa[1], a22=pa[2], a23=pa[3], a24=pa[4], a25=pa[5];
    pa = W02 + (288 + u) * 48 + 6 * kq;
    f32x2 a30=pa[0], a31=pa[1], a32=pa[2], a33=pa[3], a34=pa[4], a35=pa[5];

    // ---- Layer-2 (K=192=[Wih1|Whh1]): gates i,f,g in regs; gate o -> LDS planes ----
    const f32x2* W12 = reinterpret_cast<const f32x2*>(kq < 4 ? Wih1 : Whh1);
    const int c12 = 12 * (kq & 3);
    pa = W12 + (      u) * 48 + c12;
    f32x2 bi0=pa[0], bi1=pa[1], bi2=pa[2], bi3=pa[3], bi4 =pa[4],  bi5 =pa[5],
          bi6=pa[6], bi7=pa[7], bi8=pa[8], bi9=pa[9], bi10=pa[10], bi11=pa[11];
    pa = W12 + ( 96 + u) * 48 + c12;
    f32x2 bf0=pa[0], bf1=pa[1], bf2=pa[2], bf3=pa[3], bf4 =pa[4],  bf5 =pa[5],
          bf6=pa[6], bf7=pa[7], bf8=pa[8], bf9=pa[9], bf10=pa[10], bf11=pa[11];
    pa = W12 + (192 + u) * 48 + c12;
    f32x2 bg0=pa[0], bg1=pa[1], bg2=pa[2], bg3=pa[3], bg4 =pa[4],  bg5 =pa[5],
          bg6=pa[6], bg7=pa[7], bg8=pa[8], bg9=pa[9], bg10=pa[10], bg11=pa[11];
    pa = W12 + (288 + u) * 48 + c12;
    #pragma unroll
    for (int k = 0; k < 12; ++k) wlds2[k][tid] = pa[k];

    if (tid < HID) {
        biasb[tid] = make_float4(bih0[tid]       + bhh0[tid],
                                 bih0[ 96 + tid] + bhh0[ 96 + tid],
                                 bih0[192 + tid] + bhh0[192 + tid],
                                 bih0[288 + tid] + bhh0[288 + tid]);
        wxb[tid]   = make_float4(Wih0[tid], Wih0[96 + tid], Wih0[192 + tid], Wih0[288 + tid]);
        biasd[tid] = make_float4(bih1[tid]       + bhh1[tid],
                                 bih1[ 96 + tid] + bhh1[ 96 + tid],
                                 bih1[192 + tid] + bhh1[192 + tid],
                                 bih1[288 + tid] + bhh1[288 + tid]);
        wls[tid]   = Wl[tid];
    }
    if (tid < 2 * HID) { h1b[tid] = 0.0f; h2b[tid] = 0.0f; }

    float c1 = 0.0f, c2 = 0.0f;   // replicated across the 8 lanes of each unit
    __syncthreads();

    #pragma unroll 1
    for (int t = 0; t < TLEN; ++t) {
        const int rd = t & 1, wb = rd ^ 1;
        int zr;
        asm volatile("v_mov_b32 %0, 0" : "=v"(zr));  // defeats LICM on LDS data

        // ---- A: L1 dots (native-pair pk_fma) + fused pointwise (all lanes) ----
        {
            const f32x2* hA = reinterpret_cast<const f32x2*>(h1b + rd * HID) + 6 * kq + zr;
            f32x2 q0 = {0,0}, q1 = {0,0}, q2 = {0,0}, q3 = {0,0};
            f32x2 h;
            h = hA[0]; PKFMA(q0,a00,h); PKFMA(q1,a10,h); PKFMA(q2,a20,h); PKFMA(q3,a30,h);
            h = hA[1]; PKFMA(q0,a01,h); PKFMA(q1,a11,h); PKFMA(q2,a21,h); PKFMA(q3,a31,h);
            h = hA[2]; PKFMA(q0,a02,h); PKFMA(q1,a12,h); PKFMA(q2,a22,h); PKFMA(q3,a32,h);
            h = hA[3]; PKFMA(q0,a03,h); PKFMA(q1,a13,h); PKFMA(q2,a23,h); PKFMA(q3,a33,h);
            h = hA[4]; PKFMA(q0,a04,h); PKFMA(q1,a14,h); PKFMA(q2,a24,h); PKFMA(q3,a34,h);
            h = hA[5]; PKFMA(q0,a05,h); PKFMA(q1,a15,h); PKFMA(q2,a25,h); PKFMA(q3,a35,h);
            float s0 = q0[0] + q0[1];
            float s1 = q1[0] + q1[1];
            float s2 = q2[0] + q2[1];
            float s3 = q3[0] + q3[1];
            RED8(s0) RED8(s1) RED8(s2) RED8(s3)
            float4 bb = *(biasb + u + zr);
            float4 wx = *(wxb + u + zr);
            const float xt = x_s[t];
            float gi = sigf(fmaf(wx.x, xt, s0 + bb.x));
            float gf = sigf(fmaf(wx.y, xt, s1 + bb.y));
            float gg = tanh_fast(fmaf(wx.z, xt, s2 + bb.z));
            float go = sigf(fmaf(wx.w, xt, s3 + bb.w));
            c1 = gf * c1 + gi * gg;
            float h1v = go * tanh_fast(c1);
            if (kq == 0) h1b[wb * HID + u] = h1v;
        }
        __syncthreads();   // the ONLY barrier per step (audit as R15)
        // ---- C: L2 dots + fused pointwise + head atomic ----
        {
            const f32x2* hC = (kq < 4)
                ? reinterpret_cast<const f32x2*>(h1b + wb * HID) + 12 * kq + zr
                : reinterpret_cast<const f32x2*>(h2b + rd * HID) + 12 * (kq - 4) + zr;
            const f32x2* wl = &wlds2[0][0] + tid + zr;   // wl[k*NTHR] = wlds2[k][tid]
            f32x2 q0 = {0,0}, q1 = {0,0}, q2 = {0,0}, q3 = {0,0};
            f32x2 h;
            h = hC[0];  PKFMA(q0,bi0,h);  PKFMA(q1,bf0,h);  PKFMA(q2,bg0,h);  PKFMA(q3,wl[ 0*NTHR],h);
            h = hC[1];  PKFMA(q0,bi1,h);  PKFMA(q1,bf1,h);  PKFMA(q2,bg1,h);  PKFMA(q3,wl[ 1*NTHR],h);
            h = hC[2];  PKFMA(q0,bi2,h);  PKFMA(q1,bf2,h);  PKFMA(q2,bg2,h);  PKFMA(q3,wl[ 2*NTHR],h);
            h = hC[3];  PKFMA(q0,bi3,h);  PKFMA(q1,bf3,h);  PKFMA(q2,bg3,h);  PKFMA(q3,wl[ 3*NTHR],h);
            h = hC[4];  PKFMA(q0,bi4,h);  PKFMA(q1,bf4,h);  PKFMA(q2,bg4,h);  PKFMA(q3,wl[ 4*NTHR],h);
            h = hC[5];  PKFMA(q0,bi5,h);  PKFMA(q1,bf5,h);  PKFMA(q2,bg5,h);  PKFMA(q3,wl[ 5*NTHR],h);
            h = hC[6];  PKFMA(q0,bi6,h);  PKFMA(q1,bf6,h);  PKFMA(q2,bg6,h);  PKFMA(q3,wl[ 6*NTHR],h);
            h = hC[7];  PKFMA(q0,bi7,h);  PKFMA(q1,bf7,h);  PKFMA(q2,bg7,h);  PKFMA(q3,wl[ 7*NTHR],h);
            h = hC[8];  PKFMA(q0,bi8,h);  PKFMA(q1,bf8,h);  PKFMA(q2,bg8,h);  PKFMA(q3,wl[ 8*NTHR],h);
            h = hC[9];  PKFMA(q0,bi9,h);  PKFMA(q1,bf9,h);  PKFMA(q2,bg9,h);  PKFMA(q3,wl[ 9*NTHR],h);
            h = hC[10]; PKFMA(q0,bi10,h); PKFMA(q1,bf10,h); PKFMA(q2,bg10,h); PKFMA(q3,wl[10*NTHR],h);
            h = hC[11]; PKFMA(q0,bi11,h); PKFMA(q1,bf11,h); PKFMA(q2,bg11,h); PKFMA(q3,wl[11*NTHR],h);
            float s0 = q0[0] + q0[1];
            float s1 = q1[0] + q1[1];
            float s2 = q2[0] + q2[1];
            float s3 = q3[0] + q3[1];
            RED8(s0) RED8(s1) RED8(s2) RED8(s3)
            float4 bd = *(biasd + u + zr);
            float gi = sigf(s0 + bd.x);
            float gf = sigf(s1 + bd.y);
            float gg = tanh_fast(s2 + bd.z);
            float go = sigf(s3 + bd.w);
            c2 = gf * c2 + gi * gg;
            float h2v = go * tanh_fast(c2);
            if (kq == 0) {
                h2b[wb * HID + u] = h2v;
                atomicAdd(&out_s[t], *(wls + u + zr) * h2v);  // fire-and-forget
            }
        }
        // 1-barrier race audit (unchanged from R15): A(t+1) writes h1b[rd(t)],
        // whose readers all ran before barrier(t); C's h2b conflicts separated
        // by barrier(t+1); h1b[wb(t)] read-only in C(t)/A(t+1).
    }
    __syncthreads();
    const float bl0 = bl[0];
    for (int i = tid; i < TLEN; i += NTHR) out[b * TLEN + i] = out_s[i] + bl0;
}

extern "C" void kernel_launch(void* const* d_in, const int* in_sizes, int n_in,
                              void* d_out, int out_size, void* d_ws, size_t ws_size,
                              hipStream_t stream)
{
    (void)in_sizes; (void)n_in; (void)d_ws; (void)ws_size; (void)out_size;
    const float* x    = (const float*)d_in[0];
    const float* Wih0 = (const float*)d_in[1];
    const float* Whh0 = (const float*)d_in[2];
    const float* bih0 = (const float*)d_in[3];
    const float* bhh0 = (const float*)d_in[4];
    const float* Wih1 = (const float*)d_in[5];
    const float* Whh1 = (const float*)d_in[6];
    const float* bih1 = (const float*)d_in[7];
    const float* bhh1 = (const float*)d_in[8];
    const float* Wl   = (const float*)d_in[9];
    const float* bl   = (const float*)d_in[10];

    lstm2_fused<<<dim3(256), dim3(NTHR), 0, stream>>>(
        x, Wih0, Whh0, bih0, bhh0, Wih1, Whh1, bih1, bhh1, Wl, bl,
        (float*)d_out);
}

// Round 17
// 2579.163 us; speedup vs baseline: 1.0205x; 1.0205x over previous
//
#include <hip/hip_runtime.h>

#define TLEN  1024
#define HID   96
#define NSAMP 16     // samples per block
#define NTHR  512    // 8 waves
#define XSTR  1025   // fp32 row stride for x_s (pad 1 -> banks spread)
#define OSTR  1025
#define HSTR  104    // f16 row stride for H buffers: 208B = 13*16B (odd 16B-blocks)

typedef _Float16 f16x8 __attribute__((ext_vector_type(8)));
typedef float    f32x4 __attribute__((ext_vector_type(4)));

__device__ __forceinline__ float sigf(float v) { return 1.0f / (1.0f + __expf(-v)); }
__device__ __forceinline__ float tanh_fast(float v) {
    float e = __expf(2.0f * v);
    return 1.0f - 2.0f / (e + 1.0f);
}

// load 8 consecutive fp32 weights, convert to an fp16 A-fragment slice
__device__ __forceinline__ f16x8 cvt_frag(const float* base) {
    const float4* q = reinterpret_cast<const float4*>(base);
    float4 v0 = q[0], v1 = q[1];
    f16x8 r;
    r[0] = (_Float16)v0.x; r[1] = (_Float16)v0.y;
    r[2] = (_Float16)v0.z; r[3] = (_Float16)v0.w;
    r[4] = (_Float16)v1.x; r[5] = (_Float16)v1.y;
    r[6] = (_Float16)v1.z; r[7] = (_Float16)v1.w;
    return r;
}

extern "C" __global__ void __launch_bounds__(NTHR)
lstm2_mfma(const float* __restrict__ x,
           const float* __restrict__ Wih0, const float* __restrict__ Whh0,
           const float* __restrict__ bih0, const float* __restrict__ bhh0,
           const float* __restrict__ Wih1, const float* __restrict__ Whh1,
           const float* __restrict__ bih1, const float* __restrict__ bhh1,
           const float* __restrict__ Wl,   const float* __restrict__ bl,
           float* __restrict__ out)
{
    // ~144.5 KB LDS -> 1 block/CU; 8 waves = 2/SIMD -> 256-VGPR budget (no spill)
    __shared__ __attribute__((aligned(16))) float    x_s[NSAMP * XSTR];
    __shared__ __attribute__((aligned(16))) float    out_s[NSAMP * OSTR];
    __shared__ __attribute__((aligned(16))) _Float16 h1b[2 * NSAMP * HSTR];
    __shared__ __attribute__((aligned(16))) _Float16 h2b[2 * NSAMP * HSTR];

    const int tid  = threadIdx.x;
    const int lane = tid & 63;
    const int wv   = tid >> 6;      // wave 0..7; owns M-tiles wv*3..wv*3+2
    const int n    = lane & 15;     // MFMA col = sample index
    const int kg   = lane >> 4;     // k-group 0..3
    const int blk  = blockIdx.x;    // 0..15, 16 samples each

    for (int i = tid; i < NSAMP * TLEN; i += NTHR) {
        int s = i >> 10, t = i & (TLEN - 1);
        x_s[s * XSTR + t]   = x[(blk * NSAMP + s) * TLEN + t];
        out_s[s * OSTR + t] = 0.0f;
    }
    for (int i = tid; i < 2 * NSAMP * HSTR; i += NTHR) {
        h1b[i] = (_Float16)0.0f;
        h2b[i] = (_Float16)0.0f;
    }

    // Weights row-PERMUTED: row' = 4*unit + gate  (torch row = gate*96 + unit).
    // A-frag (16x16x32): lane holds A[row'=tile*16+(lane&15)][k = kg*8 + j + 32c].
    // Consistency of the same k-map on A and B makes D correct for any HW k-perm;
    // C/D mapping (col=lane&15, row=(lane>>4)*4+reg) is the m89-verified one.
    f16x8 A1[3][3], A2[3][6];
    float bb1[3][4], wx1[3][4], bb2[3][4], wlv[3];
    #pragma unroll
    for (int mi = 0; mi < 3; ++mi) {
        const int rp   = (wv * 3 + mi) * 16 + (lane & 15);
        const int orow = (rp & 3) * HID + (rp >> 2);   // gate*96 + unit
        #pragma unroll
        for (int c = 0; c < 3; ++c)
            A1[mi][c] = cvt_frag(Whh0 + orow * HID + c * 32 + kg * 8);
        #pragma unroll
        for (int c = 0; c < 6; ++c) {
            const float* bp = (c < 3) ? (Wih1 + orow * HID + c * 32 + kg * 8)
                                      : (Whh1 + orow * HID + (c - 3) * 32 + kg * 8);
            A2[mi][c] = cvt_frag(bp);
        }
        const int up = 4 * (wv * 3 + mi) + kg;   // this lane's pointwise unit
        #pragma unroll
        for (int g = 0; g < 4; ++g) {
            bb1[mi][g] = bih0[g * HID + up] + bhh0[g * HID + up];
            wx1[mi][g] = Wih0[g * HID + up];
            bb2[mi][g] = bih1[g * HID + up] + bhh1[g * HID + up];
        }
        wlv[mi] = Wl[up];
    }

    float c1[3] = {0.f, 0.f, 0.f}, c2[3] = {0.f, 0.f, 0.f};
    __syncthreads();

    #pragma unroll 1
    for (int t = 0; t < TLEN; ++t) {
        const int rd = t & 1, wb = rd ^ 1;

        // ---- L1: G1[384x16] = Whh0' x H1[96x16]; fused lane-local cell update ----
        {
            const _Float16* hb = h1b + rd * (NSAMP * HSTR) + n * HSTR + kg * 8;
            f16x8 B0 = *reinterpret_cast<const f16x8*>(hb);
            f16x8 B1 = *reinterpret_cast<const f16x8*>(hb + 32);
            f16x8 B2 = *reinterpret_cast<const f16x8*>(hb + 64);
            const float xt = x_s[n * XSTR + t];
            #pragma unroll
            for (int mi = 0; mi < 3; ++mi) {
                f32x4 acc = {0.f, 0.f, 0.f, 0.f};
                acc = __builtin_amdgcn_mfma_f32_16x16x32_f16(A1[mi][0], B0, acc, 0, 0, 0);
                acc = __builtin_amdgcn_mfma_f32_16x16x32_f16(A1[mi][1], B1, acc, 0, 0, 0);
                acc = __builtin_amdgcn_mfma_f32_16x16x32_f16(A1[mi][2], B2, acc, 0, 0, 0);
                // lane holds gates i,f,g,o (regs 0..3) of unit up for sample n
                float gi = sigf(acc[0] + bb1[mi][0] + wx1[mi][0] * xt);
                float gf = sigf(acc[1] + bb1[mi][1] + wx1[mi][1] * xt);
                float gg = tanh_fast(acc[2] + bb1[mi][2] + wx1[mi][2] * xt);
                float go = sigf(acc[3] + bb1[mi][3] + wx1[mi][3] * xt);
                c1[mi] = gf * c1[mi] + gi * gg;
                float h1v = go * tanh_fast(c1[mi]);
                const int up = 4 * (wv * 3 + mi) + kg;
                h1b[wb * (NSAMP * HSTR) + n * HSTR + up] = (_Float16)h1v;
            }
        }
        __syncthreads();
        // ---- L2: G2[384x16] = [Wih1|Whh1]' x [H1_t ; H2_{t-1}] + head ----
        {
            const _Float16* p1 = h1b + wb * (NSAMP * HSTR) + n * HSTR + kg * 8;
            const _Float16* p2 = h2b + rd * (NSAMP * HSTR) + n * HSTR + kg * 8;
            f16x8 B0 = *reinterpret_cast<const f16x8*>(p1);
            f16x8 B1 = *reinterpret_cast<const f16x8*>(p1 + 32);
            f16x8 B2 = *reinterpret_cast<const f16x8*>(p1 + 64);
            f16x8 B3 = *reinterpret_cast<const f16x8*>(p2);
            f16x8 B4 = *reinterpret_cast<const f16x8*>(p2 + 32);
            f16x8 B5 = *reinterpret_cast<const f16x8*>(p2 + 64);
            float po = 0.0f;
            #pragma unroll
            for (int mi = 0; mi < 3; ++mi) {
                f32x4 acc = {0.f, 0.f, 0.f, 0.f};
                acc = __builtin_amdgcn_mfma_f32_16x16x32_f16(A2[mi][0], B0, acc, 0, 0, 0);
                acc = __builtin_amdgcn_mfma_f32_16x16x32_f16(A2[mi][1], B1, acc, 0, 0, 0);
                acc = __builtin_amdgcn_mfma_f32_16x16x32_f16(A2[mi][2], B2, acc, 0, 0, 0);
                acc = __builtin_amdgcn_mfma_f32_16x16x32_f16(A2[mi][3], B3, acc, 0, 0, 0);
                acc = __builtin_amdgcn_mfma_f32_16x16x32_f16(A2[mi][4], B4, acc, 0, 0, 0);
                acc = __builtin_amdgcn_mfma_f32_16x16x32_f16(A2[mi][5], B5, acc, 0, 0, 0);
                float gi = sigf(acc[0] + bb2[mi][0]);
                float gf = sigf(acc[1] + bb2[mi][1]);
                float gg = tanh_fast(acc[2] + bb2[mi][2]);
                float go = sigf(acc[3] + bb2[mi][3]);
                c2[mi] = gf * c2[mi] + gi * gg;
                float h2v = go * tanh_fast(c2[mi]);
                const int up = 4 * (wv * 3 + mi) + kg;
                h2b[wb * (NSAMP * HSTR) + n * HSTR + up] = (_Float16)h2v;
                po = fmaf(wlv[mi], h2v, po);
            }
            // head: sum this wave's 12 units (kg groups) -> lane n, one atomic/wave
            po += __shfl_xor(po, 16);
            po += __shfl_xor(po, 32);
            if (lane < 16) atomicAdd(&out_s[n * OSTR + t], po);
        }
        __syncthreads();
        // race audit: L1(t+1) writes h1b[rd(t)] whose readers (L1(t) B-frags)
        // finished before barrier-1(t); L2(t+1) writes h2b[rd(t)] whose readers
        // (L2(t)) finished before barrier-2(t); all reads of buffers written
        // this step sit behind the intervening barrier.
    }

    const float bl0 = bl[0];
    for (int i = tid; i < NSAMP * TLEN; i += NTHR) {
        int s = i >> 10, t = i & (TLEN - 1);
        out[(blk * NSAMP + s) * TLEN + t] = out_s[s * OSTR + t] + bl0;
    }
}

extern "C" void kernel_launch(void* const* d_in, const int* in_sizes, int n_in,
                              void* d_out, int out_size, void* d_ws, size_t ws_size,
                              hipStream_t stream)
{
    (void)in_sizes; (void)n_in; (void)d_ws; (void)ws_size; (void)out_size;
    const float* x    = (const float*)d_in[0];
    const float* Wih0 = (const float*)d_in[1];
    const float* Whh0 = (const float*)d_in[2];
    const float* bih0 = (const float*)d_in[3];
    const float* bhh0 = (const float*)d_in[4];
    const float* Wih1 = (const float*)d_in[5];
    const float* Whh1 = (const float*)d_in[6];
    const float* bih1 = (const float*)d_in[7];
    const float* bhh1 = (const float*)d_in[8];
    const float* Wl   = (const float*)d_in[9];
    const float* bl   = (const float*)d_in[10];

    lstm2_mfma<<<dim3(16), dim3(NTHR), 0, stream>>>(
        x, Wih0, Whh0, bih0, bhh0, Wih1, Whh1, bih1, bhh1, Wl, bl,
        (float*)d_out);
}

// Round 18
// 2494.165 us; speedup vs baseline: 1.0553x; 1.0341x over previous
//
#include <hip/hip_runtime.h>

#define TLEN  1024
#define HID   96
#define NSAMP 16
#define NTHR  512
#define XSTR  1025
#define OSTR  1025
#define HSTR  104
#define HBUF  (NSAMP * HSTR)

typedef _Float16 f16x8 __attribute__((ext_vector_type(8)));
typedef float    f32x4 __attribute__((ext_vector_type(4)));

__device__ __forceinline__ float sigf(float v) { return 1.0f / (1.0f + __expf(-v)); }
__device__ __forceinline__ float tanh_fast(float v) {
    float e = __expf(2.0f * v);
    return 1.0f - 2.0f / (e + 1.0f);
}

// load 8 consecutive fp32 weights -> fp16 A-fragment slice
__device__ __forceinline__ f16x8 cvt_frag(const float* base) {
    const float4* q = reinterpret_cast<const float4*>(base);
    float4 v0 = q[0], v1 = q[1];
    f16x8 r;
    r[0] = (_Float16)v0.x; r[1] = (_Float16)v0.y;
    r[2] = (_Float16)v0.z; r[3] = (_Float16)v0.w;
    r[4] = (_Float16)v1.x; r[5] = (_Float16)v1.y;
    r[6] = (_Float16)v1.z; r[7] = (_Float16)v1.w;
    return r;
}

// Wavefront-pipelined 2-layer LSTM: waves 0-3 compute layer1(step p) while
// waves 4-7 compute layer2(step p-1) -- independent work, ONE barrier/phase.
extern "C" __global__ void __launch_bounds__(NTHR)
lstm2_pipe(const float* __restrict__ x,
           const float* __restrict__ Wih0, const float* __restrict__ Whh0,
           const float* __restrict__ bih0, const float* __restrict__ bhh0,
           const float* __restrict__ Wih1, const float* __restrict__ Whh1,
           const float* __restrict__ bih1, const float* __restrict__ bhh1,
           const float* __restrict__ Wl,   const float* __restrict__ bl,
           float* __restrict__ out)
{
    // ~144 KB LDS -> 1 block/CU -> 2 waves/SIMD -> 256-VGPR budget
    __shared__ __attribute__((aligned(16))) float    x_s[NSAMP * XSTR];
    __shared__ __attribute__((aligned(16))) float    out_s[NSAMP * OSTR];
    __shared__ __attribute__((aligned(16))) _Float16 h1b[2 * HBUF];  // h1(t) in buf (t+1)&1
    __shared__ __attribute__((aligned(16))) _Float16 h2b[2 * HBUF];  // h2(t) in buf (t+1)&1
    __shared__ __attribute__((aligned(16))) float4   bbt1[HID];      // L1 bias per unit
    __shared__ __attribute__((aligned(16))) float4   bbt2[HID];      // L2 bias per unit

    const int tid   = threadIdx.x;
    const int lane  = tid & 63;
    const int wv    = tid >> 6;     // 0..7
    const int lw    = wv & 3;       // index within role group
    const bool isL1 = (wv < 4);     // waves 0-3: layer1; 4-7: layer2
    const int n     = lane & 15;    // MFMA col = sample
    const int kg    = lane >> 4;    // k-group 0..3
    const int blk   = blockIdx.x;

    for (int i = tid; i < NSAMP * TLEN; i += NTHR) {
        int s = i >> 10, t = i & (TLEN - 1);
        x_s[s * XSTR + t]   = x[(blk * NSAMP + s) * TLEN + t];
        out_s[s * OSTR + t] = 0.0f;
    }
    for (int i = tid; i < 2 * HBUF; i += NTHR) {
        h1b[i] = (_Float16)0.0f;
        h2b[i] = (_Float16)0.0f;
    }
    if (tid < HID) {
        bbt1[tid] = make_float4(bih0[tid]       + bhh0[tid],
                                bih0[ 96 + tid] + bhh0[ 96 + tid],
                                bih0[192 + tid] + bhh0[192 + tid],
                                bih0[288 + tid] + bhh0[288 + tid]);
        bbt2[tid] = make_float4(bih1[tid]       + bhh1[tid],
                                bih1[ 96 + tid] + bhh1[ 96 + tid],
                                bih1[192 + tid] + bhh1[192 + tid],
                                bih1[288 + tid] + bhh1[288 + tid]);
    }

    // Row-permuted weights (row' = 4*unit + gate), R17-verified fragment scheme.
    // SHARED arrays across the two wave roles -> single register footprint.
    f16x8 A[6][6];
    float aux[6][4];   // L1: x-path weights (4 gates); L2: [0]=Wl[u], rest 0
    #pragma unroll
    for (int mi = 0; mi < 6; ++mi) {
        const int tile = lw * 6 + mi;
        const int rp   = tile * 16 + n;
        const int orow = (rp & 3) * HID + (rp >> 2);   // gate*96 + unit
        const int u    = tile * 4 + kg;
        if (isL1) {
            A[mi][0] = cvt_frag(Whh0 + orow * HID +  0 + kg * 8);
            A[mi][1] = cvt_frag(Whh0 + orow * HID + 32 + kg * 8);
            A[mi][2] = cvt_frag(Whh0 + orow * HID + 64 + kg * 8);
            A[mi][3] = A[mi][0]; A[mi][4] = A[mi][1]; A[mi][5] = A[mi][2]; // defined, unused
            aux[mi][0] = Wih0[u];           aux[mi][1] = Wih0[ 96 + u];
            aux[mi][2] = Wih0[192 + u];     aux[mi][3] = Wih0[288 + u];
        } else {
            A[mi][0] = cvt_frag(Wih1 + orow * HID +  0 + kg * 8);
            A[mi][1] = cvt_frag(Wih1 + orow * HID + 32 + kg * 8);
            A[mi][2] = cvt_frag(Wih1 + orow * HID + 64 + kg * 8);
            A[mi][3] = cvt_frag(Whh1 + orow * HID +  0 + kg * 8);
            A[mi][4] = cvt_frag(Whh1 + orow * HID + 32 + kg * 8);
            A[mi][5] = cvt_frag(Whh1 + orow * HID + 64 + kg * 8);
            aux[mi][0] = Wl[u]; aux[mi][1] = 0.f; aux[mi][2] = 0.f; aux[mi][3] = 0.f;
        }
    }

    float cst[6] = {0.f, 0.f, 0.f, 0.f, 0.f, 0.f};  // c1 (L1 waves) / c2 (L2 waves)
    __syncthreads();

    #pragma unroll 1
    for (int p = 0; p <= TLEN; ++p) {
        if (isL1) {
            if (p < TLEN) {
                // compute h1(p): reads h1(p-1) = buf p&1, writes buf (p+1)&1
                const _Float16* hr = h1b + (p & 1) * HBUF + n * HSTR + kg * 8;
                f16x8 B0 = *reinterpret_cast<const f16x8*>(hr);
                f16x8 B1 = *reinterpret_cast<const f16x8*>(hr + 32);
                f16x8 B2 = *reinterpret_cast<const f16x8*>(hr + 64);
                const float xt = x_s[n * XSTR + p];
                _Float16* hw = h1b + ((p + 1) & 1) * HBUF + n * HSTR + lw * 24 + kg;
                #pragma unroll
                for (int mi = 0; mi < 6; ++mi) {
                    f32x4 acc = {0.f, 0.f, 0.f, 0.f};
                    acc = __builtin_amdgcn_mfma_f32_16x16x32_f16(A[mi][0], B0, acc, 0, 0, 0);
                    acc = __builtin_amdgcn_mfma_f32_16x16x32_f16(A[mi][1], B1, acc, 0, 0, 0);
                    acc = __builtin_amdgcn_mfma_f32_16x16x32_f16(A[mi][2], B2, acc, 0, 0, 0);
                    float4 bb = bbt1[lw * 24 + mi * 4 + kg];   // broadcast read
                    float gi = sigf(fmaf(aux[mi][0], xt, acc[0] + bb.x));
                    float gf = sigf(fmaf(aux[mi][1], xt, acc[1] + bb.y));
                    float gg = tanh_fast(fmaf(aux[mi][2], xt, acc[2] + bb.z));
                    float go = sigf(fmaf(aux[mi][3], xt, acc[3] + bb.w));
                    cst[mi] = gf * cst[mi] + gi * gg;
                    float h1v = go * tanh_fast(cst[mi]);
                    hw[mi * 4] = (_Float16)h1v;
                }
            }
        } else {
            if (p >= 1) {
                // compute h2(p-1): reads h1(p-1) = buf p&1 (read-only, shared with L1),
                // reads h2(p-2) = buf (p-1)&1, writes h2(p-1) -> buf p&1 of h2b
                const _Float16* p1 = h1b + (p & 1) * HBUF + n * HSTR + kg * 8;
                const _Float16* p2 = h2b + ((p - 1) & 1) * HBUF + n * HSTR + kg * 8;
                f16x8 B0 = *reinterpret_cast<const f16x8*>(p1);
                f16x8 B1 = *reinterpret_cast<const f16x8*>(p1 + 32);
                f16x8 B2 = *reinterpret_cast<const f16x8*>(p1 + 64);
                f16x8 B3 = *reinterpret_cast<const f16x8*>(p2);
                f16x8 B4 = *reinterpret_cast<const f16x8*>(p2 + 32);
                f16x8 B5 = *reinterpret_cast<const f16x8*>(p2 + 64);
                _Float16* hw = h2b + (p & 1) * HBUF + n * HSTR + lw * 24 + kg;
                float po = 0.f;
                #pragma unroll
                for (int mi = 0; mi < 6; ++mi) {
                    f32x4 acc = {0.f, 0.f, 0.f, 0.f};
                    acc = __builtin_amdgcn_mfma_f32_16x16x32_f16(A[mi][0], B0, acc, 0, 0, 0);
                    acc = __builtin_amdgcn_mfma_f32_16x16x32_f16(A[mi][1], B1, acc, 0, 0, 0);
                    acc = __builtin_amdgcn_mfma_f32_16x16x32_f16(A[mi][2], B2, acc, 0, 0, 0);
                    acc = __builtin_amdgcn_mfma_f32_16x16x32_f16(A[mi][3], B3, acc, 0, 0, 0);
                    acc = __builtin_amdgcn_mfma_f32_16x16x32_f16(A[mi][4], B4, acc, 0, 0, 0);
                    acc = __builtin_amdgcn_mfma_f32_16x16x32_f16(A[mi][5], B5, acc, 0, 0, 0);
                    float4 bb = bbt2[lw * 24 + mi * 4 + kg];   // broadcast read
                    float gi = sigf(acc[0] + bb.x);
                    float gf = sigf(acc[1] + bb.y);
                    float gg = tanh_fast(acc[2] + bb.z);
                    float go = sigf(acc[3] + bb.w);
                    cst[mi] = gf * cst[mi] + gi * gg;
                    float h2v = go * tanh_fast(cst[mi]);
                    hw[mi * 4] = (_Float16)h2v;
                    po = fmaf(aux[mi][0], h2v, po);
                }
                po += __shfl_xor(po, 16);
                po += __shfl_xor(po, 32);
                if (lane < 16) atomicAdd(&out_s[n * OSTR + (p - 1)], po);
            }
        }
        __syncthreads();
        // race audit (single barrier): phase p+1 writes h1b[(p+2)&1]=h1b[p&1]
        // whose readers (L1+L2 at phase p... reads of h1b[p&1]) completed before
        // barrier(p). h2b[(p+1)&1] written at phase p+1 was last read at phase p
        // (as h2(p-2) buffer) -- same separation. All reads at phase p+1 target
        // buffers written at phase p, behind barrier(p).
    }

    const float bl0 = bl[0];
    for (int i = tid; i < NSAMP * TLEN; i += NTHR) {
        int s = i >> 10, t = i & (TLEN - 1);
        out[(blk * NSAMP + s) * TLEN + t] = out_s[s * OSTR + t] + bl0;
    }
}

extern "C" void kernel_launch(void* const* d_in, const int* in_sizes, int n_in,
                              void* d_out, int out_size, void* d_ws, size_t ws_size,
                              hipStream_t stream)
{
    (void)in_sizes; (void)n_in; (void)d_ws; (void)ws_size; (void)out_size;
    const float* x    = (const float*)d_in[0];
    const float* Wih0 = (const float*)d_in[1];
    const float* Whh0 = (const float*)d_in[2];
    const float* bih0 = (const float*)d_in[3];
    const float* bhh0 = (const float*)d_in[4];
    const float* Wih1 = (const float*)d_in[5];
    const float* Whh1 = (const float*)d_in[6];
    const float* bih1 = (const float*)d_in[7];
    const float* bhh1 = (const float*)d_in[8];
    const float* Wl   = (const float*)d_in[9];
    const float* bl   = (const float*)d_in[10];

    lstm2_pipe<<<dim3(16), dim3(NTHR), 0, stream>>>(
        x, Wih0, Whh0, bih0, bhh0, Wih1, Whh1, bih1, bhh1, Wl, bl,
        (float*)d_out);
}

// Round 20
// 1476.006 us; speedup vs baseline: 1.7833x; 1.6898x over previous
//
#include <hip/hip_runtime.h>

#define TLEN  1024
#define HID   96
#define NSAMP 16
#define NTHR  512
#define XSTR  1025
#define OSTR  1025
#define HSTR  104
#define HBUF  (NSAMP * HSTR)

typedef _Float16 f16x8 __attribute__((ext_vector_type(8)));
typedef float    f32x4 __attribute__((ext_vector_type(4)));

// Nonlinearities via HW v_exp_f32 (2^x) + v_rcp_f32 instead of IEEE division:
// hipcc expands a plain fp32 '/' into v_div_scale+v_rcp+v_div_fmas+v_div_fixup
// (~8-10 instr). 5 divisions per unit-update was ~40% of the phase VALU issue.
// sigf = rcp(1 + 2^(-x*log2e)); saturates correctly at +-inf.
__device__ __forceinline__ float sigf(float v) {
    float e = __builtin_amdgcn_exp2f(v * -1.44269504089f);   // exp(-v)
    return __builtin_amdgcn_rcpf(1.0f + e);
}
// tanh = 1 - 2*rcp(2^(2x*log2e) + 1); +inf -> 1, -inf -> -1.
__device__ __forceinline__ float tanh_fast(float v) {
    float e = __builtin_amdgcn_exp2f(v * 2.88539008178f);    // exp(2v)
    return fmaf(-2.0f, __builtin_amdgcn_rcpf(e + 1.0f), 1.0f);
}

// load 8 consecutive fp32 weights -> fp16 A-fragment slice
__device__ __forceinline__ f16x8 cvt_frag(const float* base) {
    const float4* q = reinterpret_cast<const float4*>(base);
    float4 v0 = q[0], v1 = q[1];
    f16x8 r;
    r[0] = (_Float16)v0.x; r[1] = (_Float16)v0.y;
    r[2] = (_Float16)v0.z; r[3] = (_Float16)v0.w;
    r[4] = (_Float16)v1.x; r[5] = (_Float16)v1.y;
    r[6] = (_Float16)v1.z; r[7] = (_Float16)v1.w;
    return r;
}

// Wavefront-pipelined 2-layer LSTM: waves 0-3 compute layer1(step p) while
// waves 4-7 compute layer2(step p-1) -- independent work, ONE barrier/phase.
extern "C" __global__ void __launch_bounds__(NTHR)
lstm2_pipe(const float* __restrict__ x,
           const float* __restrict__ Wih0, const float* __restrict__ Whh0,
           const float* __restrict__ bih0, const float* __restrict__ bhh0,
           const float* __restrict__ Wih1, const float* __restrict__ Whh1,
           const float* __restrict__ bih1, const float* __restrict__ bhh1,
           const float* __restrict__ Wl,   const float* __restrict__ bl,
           float* __restrict__ out)
{
    // ~144 KB LDS -> 1 block/CU -> 2 waves/SIMD -> 256-VGPR budget
    __shared__ __attribute__((aligned(16))) float    x_s[NSAMP * XSTR];
    __shared__ __attribute__((aligned(16))) float    out_s[NSAMP * OSTR];
    __shared__ __attribute__((aligned(16))) _Float16 h1b[2 * HBUF];
    __shared__ __attribute__((aligned(16))) _Float16 h2b[2 * HBUF];
    __shared__ __attribute__((aligned(16))) float4   bbt1[HID];
    __shared__ __attribute__((aligned(16))) float4   bbt2[HID];

    const int tid   = threadIdx.x;
    const int lane  = tid & 63;
    const int wv    = tid >> 6;     // 0..7
    const int lw    = wv & 3;       // index within role group
    const bool isL1 = (wv < 4);     // waves 0-3: layer1; 4-7: layer2
    const int n     = lane & 15;    // MFMA col = sample
    const int kg    = lane >> 4;    // k-group 0..3
    const int blk   = blockIdx.x;

    for (int i = tid; i < NSAMP * TLEN; i += NTHR) {
        int s = i >> 10, t = i & (TLEN - 1);
        x_s[s * XSTR + t]   = x[(blk * NSAMP + s) * TLEN + t];
        out_s[s * OSTR + t] = 0.0f;
    }
    for (int i = tid; i < 2 * HBUF; i += NTHR) {
        h1b[i] = (_Float16)0.0f;
        h2b[i] = (_Float16)0.0f;
    }
    if (tid < HID) {
        bbt1[tid] = make_float4(bih0[tid]       + bhh0[tid],
                                bih0[ 96 + tid] + bhh0[ 96 + tid],
                                bih0[192 + tid] + bhh0[192 + tid],
                                bih0[288 + tid] + bhh0[288 + tid]);
        bbt2[tid] = make_float4(bih1[tid]       + bhh1[tid],
                                bih1[ 96 + tid] + bhh1[ 96 + tid],
                                bih1[192 + tid] + bhh1[192 + tid],
                                bih1[288 + tid] + bhh1[288 + tid]);
    }

    // Row-permuted weights (row' = 4*unit + gate), R17-verified fragment scheme.
    f16x8 A[6][6];
    float aux[6][4];   // L1: x-path weights (4 gates); L2: [0]=Wl[u]
    #pragma unroll
    for (int mi = 0; mi < 6; ++mi) {
        const int tile = lw * 6 + mi;
        const int rp   = tile * 16 + n;
        const int orow = (rp & 3) * HID + (rp >> 2);   // gate*96 + unit
        const int u    = tile * 4 + kg;
        if (isL1) {
            A[mi][0] = cvt_frag(Whh0 + orow * HID +  0 + kg * 8);
            A[mi][1] = cvt_frag(Whh0 + orow * HID + 32 + kg * 8);
            A[mi][2] = cvt_frag(Whh0 + orow * HID + 64 + kg * 8);
            A[mi][3] = A[mi][0]; A[mi][4] = A[mi][1]; A[mi][5] = A[mi][2]; // unused
            aux[mi][0] = Wih0[u];           aux[mi][1] = Wih0[ 96 + u];
            aux[mi][2] = Wih0[192 + u];     aux[mi][3] = Wih0[288 + u];
        } else {
            A[mi][0] = cvt_frag(Wih1 + orow * HID +  0 + kg * 8);
            A[mi][1] = cvt_frag(Wih1 + orow * HID + 32 + kg * 8);
            A[mi][2] = cvt_frag(Wih1 + orow * HID + 64 + kg * 8);
            A[mi][3] = cvt_frag(Whh1 + orow * HID +  0 + kg * 8);
            A[mi][4] = cvt_frag(Whh1 + orow * HID + 32 + kg * 8);
            A[mi][5] = cvt_frag(Whh1 + orow * HID + 64 + kg * 8);
            aux[mi][0] = Wl[u]; aux[mi][1] = 0.f; aux[mi][2] = 0.f; aux[mi][3] = 0.f;
        }
    }

    float cst[6] = {0.f, 0.f, 0.f, 0.f, 0.f, 0.f};
    __syncthreads();

    #pragma unroll 1
    for (int p = 0; p <= TLEN; ++p) {
        if (isL1) {
            if (p < TLEN) {
                const _Float16* hr = h1b + (p & 1) * HBUF + n * HSTR + kg * 8;
                f16x8 B0 = *reinterpret_cast<const f16x8*>(hr);
                f16x8 B1 = *reinterpret_cast<const f16x8*>(hr + 32);
                f16x8 B2 = *reinterpret_cast<const f16x8*>(hr + 64);
                const float xt = x_s[n * XSTR + p];
                _Float16* hw = h1b + ((p + 1) & 1) * HBUF + n * HSTR + lw * 24 + kg;
                #pragma unroll
                for (int mi = 0; mi < 6; ++mi) {
                    f32x4 acc = {0.f, 0.f, 0.f, 0.f};
                    acc = __builtin_amdgcn_mfma_f32_16x16x32_f16(A[mi][0], B0, acc, 0, 0, 0);
                    acc = __builtin_amdgcn_mfma_f32_16x16x32_f16(A[mi][1], B1, acc, 0, 0, 0);
                    acc = __builtin_amdgcn_mfma_f32_16x16x32_f16(A[mi][2], B2, acc, 0, 0, 0);
                    float4 bb = bbt1[lw * 24 + mi * 4 + kg];
                    float gi = sigf(fmaf(aux[mi][0], xt, acc[0] + bb.x));
                    float gf = sigf(fmaf(aux[mi][1], xt, acc[1] + bb.y));
                    float gg = tanh_fast(fmaf(aux[mi][2], xt, acc[2] + bb.z));
                    float go = sigf(fmaf(aux[mi][3], xt, acc[3] + bb.w));
                    cst[mi] = gf * cst[mi] + gi * gg;
                    float h1v = go * tanh_fast(cst[mi]);
                    hw[mi * 4] = (_Float16)h1v;
                }
            }
        } else {
            if (p >= 1) {
                const _Float16* p1 = h1b + (p & 1) * HBUF + n * HSTR + kg * 8;
                const _Float16* p2 = h2b + ((p - 1) & 1) * HBUF + n * HSTR + kg * 8;
                f16x8 B0 = *reinterpret_cast<const f16x8*>(p1);
                f16x8 B1 = *reinterpret_cast<const f16x8*>(p1 + 32);
                f16x8 B2 = *reinterpret_cast<const f16x8*>(p1 + 64);
                f16x8 B3 = *reinterpret_cast<const f16x8*>(p2);
                f16x8 B4 = *reinterpret_cast<const f16x8*>(p2 + 32);
                f16x8 B5 = *reinterpret_cast<const f16x8*>(p2 + 64);
                _Float16* hw = h2b + (p & 1) * HBUF + n * HSTR + lw * 24 + kg;
                float po = 0.f;
                #pragma unroll
                for (int mi = 0; mi < 6; ++mi) {
                    f32x4 acc = {0.f, 0.f, 0.f, 0.f};
                    acc = __builtin_amdgcn_mfma_f32_16x16x32_f16(A[mi][0], B0, acc, 0, 0, 0);
                    acc = __builtin_amdgcn_mfma_f32_16x16x32_f16(A[mi][1], B1, acc, 0, 0, 0);
                    acc = __builtin_amdgcn_mfma_f32_16x16x32_f16(A[mi][2], B2, acc, 0, 0, 0);
                    acc = __builtin_amdgcn_mfma_f32_16x16x32_f16(A[mi][3], B3, acc, 0, 0, 0);
                    acc = __builtin_amdgcn_mfma_f32_16x16x32_f16(A[mi][4], B4, acc, 0, 0, 0);
                    acc = __builtin_amdgcn_mfma_f32_16x16x32_f16(A[mi][5], B5, acc, 0, 0, 0);
                    float4 bb = bbt2[lw * 24 + mi * 4 + kg];
                    float gi = sigf(acc[0] + bb.x);
                    float gf = sigf(acc[1] + bb.y);
                    float gg = tanh_fast(acc[2] + bb.z);
                    float go = sigf(acc[3] + bb.w);
                    cst[mi] = gf * cst[mi] + gi * gg;
                    float h2v = go * tanh_fast(cst[mi]);
                    hw[mi * 4] = (_Float16)h2v;
                    po = fmaf(aux[mi][0], h2v, po);
                }
                po += __shfl_xor(po, 16);
                po += __shfl_xor(po, 32);
                if (lane < 16) atomicAdd(&out_s[n * OSTR + (p - 1)], po);
            }
        }
        __syncthreads();
        // race audit: as R18 (verified passing) -- every conflicting buffer
        // access pair is separated by >=1 collective barrier.
    }

    const float bl0 = bl[0];
    for (int i = tid; i < NSAMP * TLEN; i += NTHR) {
        int s = i >> 10, t = i & (TLEN - 1);
        out[(blk * NSAMP + s) * TLEN + t] = out_s[s * OSTR + t] + bl0;
    }
}

extern "C" void kernel_launch(void* const* d_in, const int* in_sizes, int n_in,
                              void* d_out, int out_size, void* d_ws, size_t ws_size,
                              hipStream_t stream)
{
    (void)in_sizes; (void)n_in; (void)d_ws; (void)ws_size; (void)out_size;
    const float* x    = (const float*)d_in[0];
    const float* Wih0 = (const float*)d_in[1];
    const float* Whh0 = (const float*)d_in[2];
    const float* bih0 = (const float*)d_in[3];
    const float* bhh0 = (const float*)d_in[4];
    const float* Wih1 = (const float*)d_in[5];
    const float* Whh1 = (const float*)d_in[6];
    const float* bih1 = (const float*)d_in[7];
    const float* bhh1 = (const float*)d_in[8];
    const float* Wl   = (const float*)d_in[9];
    const float* bl   = (const float*)d_in[10];

    lstm2_pipe<<<dim3(16), dim3(NTHR), 0, stream>>>(
        x, Wih0, Whh0, bih0, bhh0, Wih1, Whh1, bih1, bhh1, Wl, bl,
        (float*)d_out);
}